// Round 4
// baseline (393.333 us; speedup 1.0000x reference)
//
#include <hip/hip_runtime.h>
#include <stdint.h>

// Problem constants
#define LSEQ 2048
#define EMB  1024
#define NH   16
#define HWID 64
#define SCALEF 0.125f   // 1/sqrt(64), folded into Q during rearrange

typedef __attribute__((ext_vector_type(4))) float  f32x4;
typedef __attribute__((ext_vector_type(8))) short  bf16x8;   // 8 bf16 in 4 VGPRs (MFMA operand)
typedef __attribute__((ext_vector_type(8))) unsigned short u16x8;
typedef __attribute__((ext_vector_type(4))) unsigned short u16x4;

static __device__ __forceinline__ unsigned short f2bf(float f) {
    union { float f; unsigned int u; } v; v.f = f;
    unsigned int r = (v.u + 0x7FFFu + ((v.u >> 16) & 1u)) >> 16;  // RNE
    return (unsigned short)r;
}
static __device__ __forceinline__ float bf2f(unsigned short h) {
    union { unsigned int u; float f; } v; v.u = ((unsigned int)h) << 16;
    return v.f;
}

static __device__ __forceinline__ void gload_lds16(const void* g, void* l) {
    __builtin_amdgcn_global_load_lds((const __attribute__((address_space(1))) void*)g,
                                     (__attribute__((address_space(3))) void*)l,
                                     16, 0, 0);
}

// ---------------------------------------------------------------------------
// K0: fp32 -> bf16 conversion of x, [w_proj;w_g] (concat as 4096x1024), w_o
// ---------------------------------------------------------------------------
__global__ __launch_bounds__(256) void convert_kernel(
    const float* __restrict__ x, const float* __restrict__ wp,
    const float* __restrict__ wg, const float* __restrict__ wo,
    unsigned short* __restrict__ xb, unsigned short* __restrict__ wcat,
    unsigned short* __restrict__ wob)
{
    const int NX  = (LSEQ * EMB) / 4;
    const int NWP = (3 * EMB * EMB) / 4;
    const int NWG = (EMB * EMB) / 4;
    const int NWO = (EMB * EMB) / 4;
    const int total = NX + NWP + NWG + NWO;
    for (int i = blockIdx.x * blockDim.x + threadIdx.x; i < total;
         i += gridDim.x * blockDim.x) {
        const float4* src; unsigned short* dst; int j;
        if (i < NX)                  { src = (const float4*)x;  dst = xb;                  j = i; }
        else if (i < NX + NWP)       { src = (const float4*)wp; dst = wcat;                j = i - NX; }
        else if (i < NX + NWP + NWG) { src = (const float4*)wg; dst = wcat + 3 * EMB * EMB; j = i - NX - NWP; }
        else                         { src = (const float4*)wo; dst = wob;                 j = i - NX - NWP - NWG; }
        float4 v = src[j];
        u16x4 o;
        o.x = f2bf(v.x); o.y = f2bf(v.y); o.z = f2bf(v.z); o.w = f2bf(v.w);
        *(u16x4*)(dst + (size_t)j * 4) = o;
    }
}

// ---------------------------------------------------------------------------
// Mask decode: tolerate bool(1B) / int32 / float32 encodings.
// ---------------------------------------------------------------------------
__global__ void decode_mask_kernel(const unsigned char* __restrict__ mask,
                                   unsigned char* __restrict__ valid)
{
    __shared__ int cnt;
    if (threadIdx.x == 0) cnt = 0;
    __syncthreads();
    int c = 0;
    for (int i = threadIdx.x; i < LSEQ; i += 256) c += (mask[i] != 0);
    atomicAdd(&cnt, c);
    __syncthreads();
    bool isbyte = cnt > LSEQ / 2;
    for (int k = threadIdx.x; k < LSEQ; k += 256) {
        unsigned char v;
        if (isbyte) v = (mask[k] != 0);
        else        v = ((mask[4*k] | mask[4*k+1] | mask[4*k+2] | mask[4*k+3]) != 0);
        valid[k] = v;
    }
}

// ---------------------------------------------------------------------------
// GEMM: C[M,N] = A[M,K] * B[N,K]^T  (m97-style 128x128, BK=64)
// ---------------------------------------------------------------------------
#define BM 128
#define BN 128
#define BK 64

__global__ __launch_bounds__(256) void gemm_bt_kernel(
    const unsigned short* __restrict__ A, const unsigned short* __restrict__ B,
    void* __restrict__ Cout, const float* __restrict__ biasN,
    int M, int N, int K, int epi)
{
    __shared__ unsigned short As[BM][BK];
    __shared__ unsigned short Bs[BN][BK];
    const int tid  = threadIdx.x;
    const int lane = tid & 63;
    const int w    = tid >> 6;
    const int wr   = w >> 1, wc = w & 1;
    const int row0 = blockIdx.y * BM;
    const int col0 = blockIdx.x * BN;
    const int lr = lane & 15;
    const int lg = lane >> 4;

    f32x4 acc[4][4];
    const f32x4 zf = {0.f, 0.f, 0.f, 0.f};
#pragma unroll
    for (int m = 0; m < 4; ++m)
#pragma unroll
        for (int n = 0; n < 4; ++n) acc[m][n] = zf;

    const char* Ab = (const char*)(A + (size_t)row0 * K);
    const char* Bb = (const char*)(B + (size_t)col0 * K);
    const int Kb = K * 2;

    for (int kt = 0; kt < K; kt += BK) {
#pragma unroll
        for (int i = 0; i < 4; ++i) {
            int o = (i * 256 + tid) * 16;
            int r = o >> 7, cb = o & 127;
            gload_lds16(Ab + (size_t)r * Kb + kt * 2 + cb, (char*)As + o);
        }
#pragma unroll
        for (int i = 0; i < 4; ++i) {
            int o = (i * 256 + tid) * 16;
            int r = o >> 7, cb = o & 127;
            gload_lds16(Bb + (size_t)r * Kb + kt * 2 + cb, (char*)Bs + o);
        }
        __syncthreads();
#pragma unroll
        for (int kk = 0; kk < 2; ++kk) {
            bf16x8 af[4], bfr[4];
            const int lk = kk * 32 + lg * 8;
#pragma unroll
            for (int m = 0; m < 4; ++m) af[m]  = *(const bf16x8*)&As[wr * 64 + m * 16 + lr][lk];
#pragma unroll
            for (int n = 0; n < 4; ++n) bfr[n] = *(const bf16x8*)&Bs[wc * 64 + n * 16 + lr][lk];
#pragma unroll
            for (int m = 0; m < 4; ++m)
#pragma unroll
                for (int n = 0; n < 4; ++n)
                    acc[m][n] = __builtin_amdgcn_mfma_f32_16x16x32_bf16(af[m], bfr[n], acc[m][n], 0, 0, 0);
        }
        __syncthreads();
    }

#pragma unroll
    for (int m = 0; m < 4; ++m)
#pragma unroll
        for (int n = 0; n < 4; ++n) {
            const int col = col0 + wc * 64 + n * 16 + lr;
#pragma unroll
            for (int r = 0; r < 4; ++r) {
                const int row = row0 + wr * 64 + m * 16 + lg * 4 + r;
                if (epi == 0)
                    ((unsigned short*)Cout)[(size_t)row * N + col] = f2bf(acc[m][n][r]);
                else
                    ((float*)Cout)[(size_t)row * N + col] = acc[m][n][r] + biasN[col];
            }
        }
}

// ---------------------------------------------------------------------------
// K2a: rearrange proj output T[L,4096]: Q (pre-scaled by 1/8) / K -> [h][l][64];
// gate -> sigmoid
// ---------------------------------------------------------------------------
__global__ __launch_bounds__(256) void rearrange_kernel(
    const unsigned short* __restrict__ T, const float* __restrict__ bg,
    unsigned short* __restrict__ Qh, unsigned short* __restrict__ Kh,
    unsigned short* __restrict__ G)
{
    const int l = blockIdx.x;
    const int t = threadIdx.x;
    const unsigned short* trow = T + (size_t)l * 4096;
    {
        const int tt = t & 127;
        const int h  = tt >> 3;
        const int c0 = (tt & 7) * 8;
        const bool isq = (t < 128);
        const int srcoff = h * 192 + (isq ? 0 : 64) + c0;
        u16x8 v = *(const u16x8*)(trow + srcoff);
        if (isq) {
            // exact: *0.125 is an exponent decrement
#pragma unroll
            for (int j = 0; j < 8; ++j) v[j] = f2bf(bf2f(v[j]) * SCALEF);
        }
        unsigned short* dst = (isq ? Qh : Kh) + ((size_t)h * LSEQ + l) * HWID + c0;
        *(u16x8*)dst = v;
    }
    {
        const int f0 = t * 4;
        float4 b4 = *(const float4*)(bg + f0);
        u16x4 tv = *(const u16x4*)(trow + 3 * EMB + f0);
        u16x4 o;
        o.x = f2bf(1.f / (1.f + __expf(-(bf2f(tv.x) + b4.x))));
        o.y = f2bf(1.f / (1.f + __expf(-(bf2f(tv.y) + b4.y))));
        o.z = f2bf(1.f / (1.f + __expf(-(bf2f(tv.z) + b4.z))));
        o.w = f2bf(1.f / (1.f + __expf(-(bf2f(tv.w) + b4.w))));
        *(u16x4*)(G + (size_t)l * EMB + f0) = o;
    }
}

// ---------------------------------------------------------------------------
// K2b: V transpose -> VT[h][c][l] via 64x64 LDS tiles
// ---------------------------------------------------------------------------
__global__ __launch_bounds__(256) void vtrans_kernel(
    const unsigned short* __restrict__ T, unsigned short* __restrict__ VT)
{
    __shared__ unsigned short tile[64][72];
    const int h  = blockIdx.x & 15;
    const int lt = blockIdx.x >> 4;
    const int l0 = lt * 64;
    const int t  = threadIdx.x;
    {
        const int i = t >> 2, c0 = (t & 3) * 16;
        const unsigned short* src = T + (size_t)(l0 + i) * 4096 + h * 192 + 128;
        *(u16x8*)&tile[i][c0]     = *(const u16x8*)(src + c0);
        *(u16x8*)&tile[i][c0 + 8] = *(const u16x8*)(src + c0 + 8);
    }
    __syncthreads();
    {
        const int c = t >> 2, j0 = (t & 3) * 16;
        unsigned short* dst = VT + ((size_t)h * HWID + c) * LSEQ + l0 + j0;
        u16x8 a, b;
#pragma unroll
        for (int j = 0; j < 8; ++j) a[j] = tile[j0 + j][c];
#pragma unroll
        for (int j = 0; j < 8; ++j) b[j] = tile[j0 + 8 + j][c];
        *(u16x8*)dst       = a;
        *(u16x8*)(dst + 8) = b;
    }
}

// ---------------------------------------------------------------------------
// K3: fused attention, barrier-free, all-register pipeline + split-k(2).
// Grid 512 = 64 qt x 4 hg x 2 sp; block 512 thr = 8 waves (4 heads x 2
// q-subtiles of 16). No __syncthreads: ps is per-wave; the 4 head-sibling
// waves share each 64B bias line through L1/L2 automatically.
// Per-iter VMEM issue order (in-order vmcnt discipline): K+valid -> V ->
// [QK] -> bias(t+1) regs -> [softmax w/ bias(t)] -> [PV]. Compiler waits:
// K-use vmcnt(6) (keeps V+bias flying), V-use vmcnt(8) (keeps bias(t+1)
// flying across the back-edge) -> bias always has ~1 iteration in flight.
// ---------------------------------------------------------------------------
__global__ __launch_bounds__(512, 4) void attn_kernel(
    const unsigned short* __restrict__ Qh, const unsigned short* __restrict__ Kh,
    const unsigned short* __restrict__ VT, const float* __restrict__ bias,
    const unsigned char* __restrict__ valid,
    float* __restrict__ Op, float* __restrict__ Ml)
{
    __shared__ unsigned short ps[8][16][40];     // per-wave P buffer, 2-way reads

    const int tid  = threadIdx.x;
    const int lane = tid & 63;
    const int w    = tid >> 6;
    // XCD map: slot = bi&7 -> (hg, sp); all blocks of a head-group+split on
    // one XCD so its L2 caches those 4 heads' K+V (2 MB).
    const int bi = blockIdx.x;
    const int hg = (bi & 7) >> 1;
    const int sp = bi & 1;
    const int qt = bi >> 3;
    const int h    = hg * 4 + (w & 3);
    const int q0b  = qt * 32;
    const int q0w  = q0b + (w >> 2) * 16;
    const int koff = sp * 1024;
    const int lr   = lane & 15;
    const int lg   = lane >> 4;

    const unsigned short* Qbase = Qh + ((size_t)h * LSEQ + q0w) * HWID;
    const bf16x8 qa0 = *(const bf16x8*)(Qbase + lr * HWID + lg * 8);
    const bf16x8 qa1 = *(const bf16x8*)(Qbase + lr * HWID + 32 + lg * 8);

    const unsigned short* Kbase = Kh + (size_t)h * LSEQ * HWID;
    const unsigned short* Vbase = VT + (size_t)h * HWID * LSEQ;

    // per-lane bias row pointers: row r -> q = q0w + lg*4 + r, key lane = lr
    const char* brow[4];
#pragma unroll
    for (int r = 0; r < 4; ++r)
        brow[r] = (const char*)bias +
                  (((size_t)(q0w + lg * 4 + r) * LSEQ + koff + lr) * NH) * 4 + h * 4;

    float mrow[4], lrow[4];
    f32x4 acc[4];
    const f32x4 zf = {0.f, 0.f, 0.f, 0.f};
#pragma unroll
    for (int r = 0; r < 4; ++r) { mrow[r] = -1e30f; lrow[r] = 0.f; }
#pragma unroll
    for (int c = 0; c < 4; ++c) acc[c] = zf;

    // prologue: bias tile 0 into loop-carried regs (kh: 0 -> k=lr, 1 -> k=16+lr)
    float bcur[2][4];
#pragma unroll
    for (int r = 0; r < 4; ++r) {
        bcur[0][r] = *(const float*)(brow[r]);
        bcur[1][r] = *(const float*)(brow[r] + 16 * NH * 4);
    }

    for (int t = 0; t < 32; ++t) {
        const int kg = koff + t * 32;

        // --- VMEM group 1: K fragments + mask bytes ---
        bf16x8 kb[2][2];
#pragma unroll
        for (int t2 = 0; t2 < 2; ++t2) {
            const unsigned short* kp = Kbase + (size_t)(kg + t2 * 16 + lr) * HWID + lg * 8;
            kb[t2][0] = *(const bf16x8*)kp;
            kb[t2][1] = *(const bf16x8*)(kp + 32);
        }
        const bool v0 = valid[kg + lr] != 0;
        const bool v1 = valid[kg + 16 + lr] != 0;

        // --- VMEM group 2: V fragments ---
        bf16x8 vb[4];
#pragma unroll
        for (int ct = 0; ct < 4; ++ct)
            vb[ct] = *(const bf16x8*)(Vbase + (size_t)(ct * 16 + lr) * LSEQ + kg + lg * 8);

        // --- QK^T (waits only for group 1) ---
        f32x4 S[2];
#pragma unroll
        for (int t2 = 0; t2 < 2; ++t2) {
            f32x4 s = zf;
            s = __builtin_amdgcn_mfma_f32_16x16x32_bf16(qa0, kb[t2][0], s, 0, 0, 0);
            s = __builtin_amdgcn_mfma_f32_16x16x32_bf16(qa1, kb[t2][1], s, 0, 0, 0);
            S[t2] = s;
        }

        // --- VMEM group 3: bias(t+1) prefetch (youngest in queue) ---
        const int nk = (t < 31) ? 32 * NH * 4 : 0;   // clamp tail (no OOB)
        float bnxt[2][4];
#pragma unroll
        for (int r = 0; r < 4; ++r) {
            bnxt[0][r] = *(const float*)(brow[r] + nk);
            bnxt[1][r] = *(const float*)(brow[r] + nk + 16 * NH * 4);
        }

        // --- softmax with bias(t) (already resident) ---
        float sc[2][4], rm[4];
#pragma unroll
        for (int r = 0; r < 4; ++r) {
            sc[0][r] = v0 ? (S[0][r] + bcur[0][r]) : -1e30f;
            sc[1][r] = v1 ? (S[1][r] + bcur[1][r]) : -1e30f;
            rm[r] = fmaxf(sc[0][r], sc[1][r]);
        }
#pragma unroll
        for (int off = 1; off < 16; off <<= 1)
#pragma unroll
            for (int r = 0; r < 4; ++r)
                rm[r] = fmaxf(rm[r], __shfl_xor(rm[r], off, 64));

        float sf[4], rs[4], p0[4], p1[4];
#pragma unroll
        for (int r = 0; r < 4; ++r) {
            const float mn = fmaxf(mrow[r], rm[r]);
            sf[r] = __expf(mrow[r] - mn);
            mrow[r] = mn;
            p0[r] = v0 ? __expf(sc[0][r] - mn) : 0.f;
            p1[r] = v1 ? __expf(sc[1][r] - mn) : 0.f;
            rs[r] = p0[r] + p1[r];
        }
#pragma unroll
        for (int off = 1; off < 16; off <<= 1)
#pragma unroll
            for (int r = 0; r < 4; ++r)
                rs[r] += __shfl_xor(rs[r], off, 64);
#pragma unroll
        for (int r = 0; r < 4; ++r) lrow[r] = lrow[r] * sf[r] + rs[r];

#pragma unroll
        for (int ct = 0; ct < 4; ++ct)
#pragma unroll
            for (int r = 0; r < 4; ++r) acc[ct][r] *= sf[r];

        // P -> per-wave LDS (S-layout write, A-frag read); lgkmcnt only
#pragma unroll
        for (int r = 0; r < 4; ++r) {
            ps[w][lg * 4 + r][lr]      = f2bf(p0[r]);
            ps[w][lg * 4 + r][16 + lr] = f2bf(p1[r]);
        }
        const bf16x8 pa = *(const bf16x8*)&ps[w][lr][lg * 8];

        // --- PV (waits vmcnt(8): V ready, bias(t+1) keeps flying) ---
#pragma unroll
        for (int ct = 0; ct < 4; ++ct)
            acc[ct] = __builtin_amdgcn_mfma_f32_16x16x32_bf16(pa, vb[ct], acc[ct], 0, 0, 0);

        // advance bias pointers + carry regs
#pragma unroll
        for (int r = 0; r < 4; ++r) brow[r] += 32 * NH * 4;
#pragma unroll
        for (int r = 0; r < 4; ++r) { bcur[0][r] = bnxt[0][r]; bcur[1][r] = bnxt[1][r]; }
    }

    // store partials (unnormalized)
    const size_t rowb = ((size_t)sp * NH + h) * LSEQ;
#pragma unroll
    for (int ct = 0; ct < 4; ++ct)
#pragma unroll
        for (int r = 0; r < 4; ++r) {
            const int q = q0w + lg * 4 + r;
            Op[(rowb + q) * HWID + ct * 16 + lr] = acc[ct][r];
        }
    if (lr == 0) {
#pragma unroll
        for (int r = 0; r < 4; ++r) {
            const int q = q0w + lg * 4 + r;
            Ml[(rowb + q) * 2 + 0] = mrow[r];
            Ml[(rowb + q) * 2 + 1] = lrow[r];
        }
    }
}

// ---------------------------------------------------------------------------
// K3b: combine split-k partials, normalize, apply gate -> bf16 Y
// ---------------------------------------------------------------------------
__global__ __launch_bounds__(256) void combine_kernel(
    const float* __restrict__ Op, const float* __restrict__ Ml,
    const unsigned short* __restrict__ G, unsigned short* __restrict__ Yb)
{
    const int t   = threadIdx.x;
    const int c   = t & 63;
    const int row = blockIdx.x * 4 + (t >> 6);      // [0, NH*LSEQ)
    const int h   = row >> 11;
    const int q   = row & (LSEQ - 1);
    const size_t r0 = (size_t)h * LSEQ + q;
    const size_t r1 = ((size_t)NH + h) * LSEQ + q;
    const float m0 = Ml[r0 * 2 + 0], l0 = Ml[r0 * 2 + 1];
    const float m1 = Ml[r1 * 2 + 0], l1 = Ml[r1 * 2 + 1];
    const float mx = fmaxf(m0, m1);
    const float a0 = __expf(m0 - mx), a1 = __expf(m1 - mx);
    const float inv = 1.f / (l0 * a0 + l1 * a1);
    const float o0 = Op[r0 * HWID + c];
    const float o1 = Op[r1 * HWID + c];
    const float y = (o0 * a0 + o1 * a1) * inv;
    const int e = h * HWID + c;
    const float g = bf2f(G[(size_t)q * EMB + e]);
    Yb[(size_t)q * EMB + e] = f2bf(y * g);
}

// ---------------------------------------------------------------------------
extern "C" void kernel_launch(void* const* d_in, const int* in_sizes, int n_in,
                              void* d_out, int out_size, void* d_ws, size_t ws_size,
                              hipStream_t stream) {
    const float*         x      = (const float*)d_in[0];
    const unsigned char* mask   = (const unsigned char*)d_in[1];
    const float*         bias   = (const float*)d_in[2];
    const float*         w_proj = (const float*)d_in[3];
    const float*         w_o    = (const float*)d_in[4];
    const float*         b_o    = (const float*)d_in[5];
    const float*         w_g    = (const float*)d_in[6];
    const float*         b_g    = (const float*)d_in[7];
    float* out = (float*)d_out;
    (void)in_sizes; (void)n_in; (void)out_size; (void)ws_size;

    char* p = (char*)d_ws;
    auto alloc = [&](size_t bytes) {
        char* r = p; p += (bytes + 255) & ~(size_t)255; return r;
    };
    unsigned short* xb    = (unsigned short*)alloc((size_t)LSEQ * EMB * 2);
    unsigned short* wcat  = (unsigned short*)alloc((size_t)4 * EMB * EMB * 2);
    unsigned short* wob   = (unsigned short*)alloc((size_t)EMB * EMB * 2);
    unsigned short* T     = (unsigned short*)alloc((size_t)LSEQ * 4096 * 2);
    unsigned short* Qh    = (unsigned short*)alloc((size_t)NH * LSEQ * HWID * 2);
    unsigned short* Kh    = (unsigned short*)alloc((size_t)NH * LSEQ * HWID * 2);
    unsigned short* VT    = (unsigned short*)alloc((size_t)NH * HWID * LSEQ * 2);
    unsigned short* G     = (unsigned short*)alloc((size_t)LSEQ * EMB * 2);
    unsigned short* Yb    = (unsigned short*)alloc((size_t)LSEQ * EMB * 2);
    unsigned char*  vmask = (unsigned char*)alloc(LSEQ);
    float*          Op    = (float*)alloc((size_t)2 * NH * LSEQ * HWID * 4);
    float*          Ml    = (float*)alloc((size_t)2 * NH * LSEQ * 2 * 4);

    convert_kernel<<<1024, 256, 0, stream>>>(x, w_proj, w_g, w_o, xb, wcat, wob);
    decode_mask_kernel<<<1, 256, 0, stream>>>(mask, vmask);
    gemm_bt_kernel<<<dim3(4096 / BN, LSEQ / BM), 256, 0, stream>>>(
        xb, wcat, (void*)T, nullptr, LSEQ, 4096, EMB, 0);
    rearrange_kernel<<<LSEQ, 256, 0, stream>>>(T, b_g, Qh, Kh, G);
    vtrans_kernel<<<NH * (LSEQ / 64), 256, 0, stream>>>(T, VT);
    attn_kernel<<<512, 512, 0, stream>>>(Qh, Kh, VT, bias, vmask, Op, Ml);
    combine_kernel<<<NH * LSEQ / 4, 256, 0, stream>>>(Op, Ml, G, Yb);
    gemm_bt_kernel<<<dim3(EMB / BN, LSEQ / BM), 256, 0, stream>>>(
        Yb, wob, (void*)out, b_o, LSEQ, EMB, EMB, 1);
}

// Round 5
// 270.180 us; speedup vs baseline: 1.4558x; 1.4558x over previous
//
#include <hip/hip_runtime.h>
#include <stdint.h>

// Problem constants
#define LSEQ 2048
#define EMB  1024
#define NH   16
#define HWID 64
#define SCALEF 0.125f   // 1/sqrt(64), folded into Q during rearrange

typedef __attribute__((ext_vector_type(4))) float  f32x4;
typedef __attribute__((ext_vector_type(8))) short  bf16x8;   // 8 bf16 in 4 VGPRs (MFMA operand)
typedef __attribute__((ext_vector_type(8))) unsigned short u16x8;
typedef __attribute__((ext_vector_type(4))) unsigned short u16x4;

static __device__ __forceinline__ unsigned short f2bf(float f) {
    union { float f; unsigned int u; } v; v.f = f;
    unsigned int r = (v.u + 0x7FFFu + ((v.u >> 16) & 1u)) >> 16;  // RNE
    return (unsigned short)r;
}
static __device__ __forceinline__ float bf2f(unsigned short h) {
    union { unsigned int u; float f; } v; v.u = ((unsigned int)h) << 16;
    return v.f;
}

static __device__ __forceinline__ void gload_lds16(const void* g, void* l) {
    __builtin_amdgcn_global_load_lds((const __attribute__((address_space(1))) void*)g,
                                     (__attribute__((address_space(3))) void*)l,
                                     16, 0, 0);
}

// ---------------------------------------------------------------------------
// K0: fp32 -> bf16 conversion of x, [w_proj;w_g] (concat as 4096x1024), w_o
// ---------------------------------------------------------------------------
__global__ __launch_bounds__(256) void convert_kernel(
    const float* __restrict__ x, const float* __restrict__ wp,
    const float* __restrict__ wg, const float* __restrict__ wo,
    unsigned short* __restrict__ xb, unsigned short* __restrict__ wcat,
    unsigned short* __restrict__ wob)
{
    const int NX  = (LSEQ * EMB) / 4;
    const int NWP = (3 * EMB * EMB) / 4;
    const int NWG = (EMB * EMB) / 4;
    const int NWO = (EMB * EMB) / 4;
    const int total = NX + NWP + NWG + NWO;
    for (int i = blockIdx.x * blockDim.x + threadIdx.x; i < total;
         i += gridDim.x * blockDim.x) {
        const float4* src; unsigned short* dst; int j;
        if (i < NX)                  { src = (const float4*)x;  dst = xb;                  j = i; }
        else if (i < NX + NWP)       { src = (const float4*)wp; dst = wcat;                j = i - NX; }
        else if (i < NX + NWP + NWG) { src = (const float4*)wg; dst = wcat + 3 * EMB * EMB; j = i - NX - NWP; }
        else                         { src = (const float4*)wo; dst = wob;                 j = i - NX - NWP - NWG; }
        float4 v = src[j];
        u16x4 o;
        o.x = f2bf(v.x); o.y = f2bf(v.y); o.z = f2bf(v.z); o.w = f2bf(v.w);
        *(u16x4*)(dst + (size_t)j * 4) = o;
    }
}

// ---------------------------------------------------------------------------
// Mask decode: tolerate bool(1B) / int32 / float32 encodings.
// ---------------------------------------------------------------------------
__global__ void decode_mask_kernel(const unsigned char* __restrict__ mask,
                                   unsigned char* __restrict__ valid)
{
    __shared__ int cnt;
    if (threadIdx.x == 0) cnt = 0;
    __syncthreads();
    int c = 0;
    for (int i = threadIdx.x; i < LSEQ; i += 256) c += (mask[i] != 0);
    atomicAdd(&cnt, c);
    __syncthreads();
    bool isbyte = cnt > LSEQ / 2;
    for (int k = threadIdx.x; k < LSEQ; k += 256) {
        unsigned char v;
        if (isbyte) v = (mask[k] != 0);
        else        v = ((mask[4*k] | mask[4*k+1] | mask[4*k+2] | mask[4*k+3]) != 0);
        valid[k] = v;
    }
}

// ---------------------------------------------------------------------------
// GEMM: C[M,N] = A[M,K] * B[N,K]^T  (m97-style 128x128, BK=64)
// ---------------------------------------------------------------------------
#define BM 128
#define BN 128
#define BK 64

__global__ __launch_bounds__(256) void gemm_bt_kernel(
    const unsigned short* __restrict__ A, const unsigned short* __restrict__ B,
    void* __restrict__ Cout, const float* __restrict__ biasN,
    int M, int N, int K, int epi)
{
    __shared__ unsigned short As[BM][BK];
    __shared__ unsigned short Bs[BN][BK];
    const int tid  = threadIdx.x;
    const int lane = tid & 63;
    const int w    = tid >> 6;
    const int wr   = w >> 1, wc = w & 1;
    const int row0 = blockIdx.y * BM;
    const int col0 = blockIdx.x * BN;
    const int lr = lane & 15;
    const int lg = lane >> 4;

    f32x4 acc[4][4];
    const f32x4 zf = {0.f, 0.f, 0.f, 0.f};
#pragma unroll
    for (int m = 0; m < 4; ++m)
#pragma unroll
        for (int n = 0; n < 4; ++n) acc[m][n] = zf;

    const char* Ab = (const char*)(A + (size_t)row0 * K);
    const char* Bb = (const char*)(B + (size_t)col0 * K);
    const int Kb = K * 2;

    for (int kt = 0; kt < K; kt += BK) {
#pragma unroll
        for (int i = 0; i < 4; ++i) {
            int o = (i * 256 + tid) * 16;
            int r = o >> 7, cb = o & 127;
            gload_lds16(Ab + (size_t)r * Kb + kt * 2 + cb, (char*)As + o);
        }
#pragma unroll
        for (int i = 0; i < 4; ++i) {
            int o = (i * 256 + tid) * 16;
            int r = o >> 7, cb = o & 127;
            gload_lds16(Bb + (size_t)r * Kb + kt * 2 + cb, (char*)Bs + o);
        }
        __syncthreads();
#pragma unroll
        for (int kk = 0; kk < 2; ++kk) {
            bf16x8 af[4], bfr[4];
            const int lk = kk * 32 + lg * 8;
#pragma unroll
            for (int m = 0; m < 4; ++m) af[m]  = *(const bf16x8*)&As[wr * 64 + m * 16 + lr][lk];
#pragma unroll
            for (int n = 0; n < 4; ++n) bfr[n] = *(const bf16x8*)&Bs[wc * 64 + n * 16 + lr][lk];
#pragma unroll
            for (int m = 0; m < 4; ++m)
#pragma unroll
                for (int n = 0; n < 4; ++n)
                    acc[m][n] = __builtin_amdgcn_mfma_f32_16x16x32_bf16(af[m], bfr[n], acc[m][n], 0, 0, 0);
        }
        __syncthreads();
    }

#pragma unroll
    for (int m = 0; m < 4; ++m)
#pragma unroll
        for (int n = 0; n < 4; ++n) {
            const int col = col0 + wc * 64 + n * 16 + lr;
#pragma unroll
            for (int r = 0; r < 4; ++r) {
                const int row = row0 + wr * 64 + m * 16 + lg * 4 + r;
                if (epi == 0)
                    ((unsigned short*)Cout)[(size_t)row * N + col] = f2bf(acc[m][n][r]);
                else
                    ((float*)Cout)[(size_t)row * N + col] = acc[m][n][r] + biasN[col];
            }
        }
}

// ---------------------------------------------------------------------------
// K2a: rearrange proj output T[L,4096]: Q (pre-scaled by 1/8) / K -> [h][l][64];
// gate -> sigmoid
// ---------------------------------------------------------------------------
__global__ __launch_bounds__(256) void rearrange_kernel(
    const unsigned short* __restrict__ T, const float* __restrict__ bg,
    unsigned short* __restrict__ Qh, unsigned short* __restrict__ Kh,
    unsigned short* __restrict__ G)
{
    const int l = blockIdx.x;
    const int t = threadIdx.x;
    const unsigned short* trow = T + (size_t)l * 4096;
    {
        const int tt = t & 127;
        const int h  = tt >> 3;
        const int c0 = (tt & 7) * 8;
        const bool isq = (t < 128);
        const int srcoff = h * 192 + (isq ? 0 : 64) + c0;
        u16x8 v = *(const u16x8*)(trow + srcoff);
        if (isq) {
#pragma unroll
            for (int j = 0; j < 8; ++j) v[j] = f2bf(bf2f(v[j]) * SCALEF);
        }
        unsigned short* dst = (isq ? Qh : Kh) + ((size_t)h * LSEQ + l) * HWID + c0;
        *(u16x8*)dst = v;
    }
    {
        const int f0 = t * 4;
        float4 b4 = *(const float4*)(bg + f0);
        u16x4 tv = *(const u16x4*)(trow + 3 * EMB + f0);
        u16x4 o;
        o.x = f2bf(1.f / (1.f + __expf(-(bf2f(tv.x) + b4.x))));
        o.y = f2bf(1.f / (1.f + __expf(-(bf2f(tv.y) + b4.y))));
        o.z = f2bf(1.f / (1.f + __expf(-(bf2f(tv.z) + b4.z))));
        o.w = f2bf(1.f / (1.f + __expf(-(bf2f(tv.w) + b4.w))));
        *(u16x4*)(G + (size_t)l * EMB + f0) = o;
    }
}

// ---------------------------------------------------------------------------
// K2b: V transpose -> VT[h][c][l] via 64x64 LDS tiles
// ---------------------------------------------------------------------------
__global__ __launch_bounds__(256) void vtrans_kernel(
    const unsigned short* __restrict__ T, unsigned short* __restrict__ VT)
{
    __shared__ unsigned short tile[64][72];
    const int h  = blockIdx.x & 15;
    const int lt = blockIdx.x >> 4;
    const int l0 = lt * 64;
    const int t  = threadIdx.x;
    {
        const int i = t >> 2, c0 = (t & 3) * 16;
        const unsigned short* src = T + (size_t)(l0 + i) * 4096 + h * 192 + 128;
        *(u16x8*)&tile[i][c0]     = *(const u16x8*)(src + c0);
        *(u16x8*)&tile[i][c0 + 8] = *(const u16x8*)(src + c0 + 8);
    }
    __syncthreads();
    {
        const int c = t >> 2, j0 = (t & 3) * 16;
        unsigned short* dst = VT + ((size_t)h * HWID + c) * LSEQ + l0 + j0;
        u16x8 a, b;
#pragma unroll
        for (int j = 0; j < 8; ++j) a[j] = tile[j0 + j][c];
#pragma unroll
        for (int j = 0; j < 8; ++j) b[j] = tile[j0 + 8 + j][c];
        *(u16x8*)dst       = a;
        *(u16x8*)(dst + 8) = b;
    }
}

// ---------------------------------------------------------------------------
// K3: fused attention — all-LDS-consumption ring pipeline.
// Grid 256 (= 1 block/CU): 64 qt x 4 hg; block 512 thr = 8 waves
// (4 heads x 2 q-subtiles of 16). KT=32.
// The ONLY vmem ops in the loop are global_load_lds stage ops (bias+K+V,
// 6/thread/tile) into a 2-slot ring. All body consumption is ds_read
// (lgkmcnt), so nothing ever force-drains the stage queue; the explicit
// vmcnt(6) at the loop top is the only drain point -> stage(t+2) flies
// for ~2 full bodies. Two raw s_barriers per body, no waitcnt-0 anywhere.
// qt-major XCD swizzle: the 4 head-sibling blocks of a q-tile share each
// 64B bias line within one XCD's L2 (exactly-once fetch).
// ---------------------------------------------------------------------------
#define SLOT 49152   // bias 16K | K 16K | V 16K

__global__ __launch_bounds__(512) void attn_kernel(
    const unsigned short* __restrict__ Qh, const unsigned short* __restrict__ Kh,
    const unsigned short* __restrict__ VT, const unsigned short* __restrict__ G,
    const float* __restrict__ bias, const unsigned char* __restrict__ valid,
    unsigned short* __restrict__ Y)
{
    __shared__ char ring[2][SLOT];               // 96 KB
    __shared__ unsigned short ps[8][16][40];     // 10 KB per-wave P buffers
    __shared__ unsigned char vld[LSEQ];          // 2 KB

    const int tid  = threadIdx.x;
    const int lane = tid & 63;
    const int w    = tid >> 6;
    // qt-major XCD swizzle: XCD = bi&7 = qt%8; 4 hg siblings co-XCD.
    const int bi = blockIdx.x;
    const int c8 = bi & 7;
    const int j  = bi >> 3;            // 0..31
    const int qt = (j >> 2) * 8 + c8;  // 0..63
    const int hg = j & 3;
    const int h4 = hg * 4;
    const int h    = h4 + (w & 3);
    const int q0b  = qt * 32;
    const int q0w  = q0b + (w >> 2) * 16;
    const int lr   = lane & 15;
    const int lg   = lane >> 4;
    const int hloc = w & 3;
    const int qloc = (w >> 2) * 16 + lg * 4;  // block-local q of this lane's row 0

    // Q fragments (registers for the whole kernel)
    const unsigned short* Qbase = Qh + ((size_t)h * LSEQ + q0w) * HWID;
    const bf16x8 qa0 = *(const bf16x8*)(Qbase + lr * HWID + lg * 8);
    const bf16x8 qa1 = *(const bf16x8*)(Qbase + lr * HWID + 32 + lg * 8);

    // mask -> LDS
    {
        uchar4 m4 = *(const uchar4*)(valid + tid * 4);
        *(uchar4*)(vld + tid * 4) = m4;
    }
    __syncthreads();   // one-time full sync (drains everything; loop never does)

    const char* bias_base = (const char*)bias;
    const unsigned short* Khb = Kh;
    const unsigned short* VTb = VT;

    // stage tile t into ring[t&1]: 6 x 16B gload_lds per thread
    auto stage = [&](int t) {
        char* base = ring[t & 1];
        const int kg = t * 32;
#pragma unroll
        for (int p = 0; p < 2; ++p) {       // bias: 32q x 32k float4 (head group)
            const int jj = p * 512 + tid;
            const int q = jj >> 5, k = jj & 31;
            gload_lds16(bias_base + (((size_t)(q0b + q) * LSEQ + kg + k) * NH + h4) * 4,
                        base + jj * 16);
        }
#pragma unroll
        for (int p = 0; p < 2; ++p) {       // K: [hloc][32k][64c] bf16
            const int jj = p * 512 + tid;
            const int hl = jj >> 8, k = (jj >> 3) & 31, cc = (jj & 7) * 8;
            gload_lds16(Khb + ((size_t)(h4 + hl) * LSEQ + kg + k) * HWID + cc,
                        base + 16384 + jj * 16);
        }
#pragma unroll
        for (int p = 0; p < 2; ++p) {       // V: [hloc][64c][32k] bf16
            const int jj = p * 512 + tid;
            const int hl = jj >> 8, cv = (jj >> 2) & 63, k16 = jj & 3;
            gload_lds16(VTb + ((size_t)(h4 + hl) * HWID + cv) * LSEQ + kg + k16 * 8,
                        base + 32768 + jj * 16);
        }
    };

    float mrow[4], lrow[4];
    f32x4 acc[4];
    const f32x4 zf = {0.f, 0.f, 0.f, 0.f};
#pragma unroll
    for (int r = 0; r < 4; ++r) { mrow[r] = -1e30f; lrow[r] = 0.f; }
#pragma unroll
    for (int c = 0; c < 4; ++c) acc[c] = zf;

    stage(0);
    stage(1);

    for (int t = 0; t < 64; ++t) {
        asm volatile("s_waitcnt vmcnt(6)" ::: "memory");
        __builtin_amdgcn_s_barrier();
        asm volatile("" ::: "memory");

        const char* base = ring[t & 1];
        const int kg = t * 32;

        // K fragments from LDS: klds[hloc][k][c]
        const unsigned short* klds = (const unsigned short*)(base + 16384);
        bf16x8 kb[2][2];
#pragma unroll
        for (int t2 = 0; t2 < 2; ++t2) {
            const unsigned short* kp = klds + (hloc * 32 + t2 * 16 + lr) * HWID + lg * 8;
            kb[t2][0] = *(const bf16x8*)kp;
            kb[t2][1] = *(const bf16x8*)(kp + 32);
        }

        // QK^T
        f32x4 S[2];
#pragma unroll
        for (int t2 = 0; t2 < 2; ++t2) {
            f32x4 s = zf;
            s = __builtin_amdgcn_mfma_f32_16x16x32_bf16(qa0, kb[t2][0], s, 0, 0, 0);
            s = __builtin_amdgcn_mfma_f32_16x16x32_bf16(qa1, kb[t2][1], s, 0, 0, 0);
            S[t2] = s;
        }

        const bool v0 = vld[kg + lr] != 0;
        const bool v1 = vld[kg + 16 + lr] != 0;

        // bias from LDS: [32q][32k] float4, component hloc (pre-offset pointer)
        const float* bsf = (const float*)base + hloc;
        float sc[2][4], rm[4];
#pragma unroll
        for (int r = 0; r < 4; ++r) {
            const float b0 = bsf[((qloc + r) * 32 + lr) * 4];
            const float b1 = bsf[((qloc + r) * 32 + 16 + lr) * 4];
            sc[0][r] = v0 ? (S[0][r] + b0) : -1e30f;
            sc[1][r] = v1 ? (S[1][r] + b1) : -1e30f;
            rm[r] = fmaxf(sc[0][r], sc[1][r]);
        }
#pragma unroll
        for (int off = 1; off < 16; off <<= 1)
#pragma unroll
            for (int r = 0; r < 4; ++r)
                rm[r] = fmaxf(rm[r], __shfl_xor(rm[r], off, 64));

        float sf[4], rs[4], p0[4], p1[4];
#pragma unroll
        for (int r = 0; r < 4; ++r) {
            const float mn = fmaxf(mrow[r], rm[r]);
            sf[r] = __expf(mrow[r] - mn);
            mrow[r] = mn;
            p0[r] = v0 ? __expf(sc[0][r] - mn) : 0.f;
            p1[r] = v1 ? __expf(sc[1][r] - mn) : 0.f;
            rs[r] = p0[r] + p1[r];
        }
#pragma unroll
        for (int off = 1; off < 16; off <<= 1)
#pragma unroll
            for (int r = 0; r < 4; ++r)
                rs[r] += __shfl_xor(rs[r], off, 64);
#pragma unroll
        for (int r = 0; r < 4; ++r) lrow[r] = lrow[r] * sf[r] + rs[r];

#pragma unroll
        for (int ct = 0; ct < 4; ++ct)
#pragma unroll
            for (int r = 0; r < 4; ++r) acc[ct][r] *= sf[r];

        // P -> per-wave LDS (S-layout write, A-frag read)
#pragma unroll
        for (int r = 0; r < 4; ++r) {
            ps[w][lg * 4 + r][lr]      = f2bf(p0[r]);
            ps[w][lg * 4 + r][16 + lr] = f2bf(p1[r]);
        }
        const bf16x8 pa = *(const bf16x8*)&ps[w][lr][lg * 8];

        // V fragments from LDS: vlds[hloc][c][k]
        const unsigned short* vlds = (const unsigned short*)(base + 32768);
#pragma unroll
        for (int ct = 0; ct < 4; ++ct) {
            bf16x8 vb = *(const bf16x8*)(vlds + (hloc * HWID + ct * 16 + lr) * 32 + lg * 8);
            acc[ct] = __builtin_amdgcn_mfma_f32_16x16x32_bf16(pa, vb, acc[ct], 0, 0, 0);
        }

        asm volatile("" ::: "memory");
        __builtin_amdgcn_s_barrier();        // all reads of this slot done
        asm volatile("" ::: "memory");
        if (t + 2 < 64) stage(t + 2);
    }

    // epilogue: normalize, gate, write bf16 Y
    float inv[4];
#pragma unroll
    for (int r = 0; r < 4; ++r) inv[r] = 1.f / lrow[r];
#pragma unroll
    for (int ct = 0; ct < 4; ++ct)
#pragma unroll
        for (int r = 0; r < 4; ++r) {
            const int q = q0w + lg * 4 + r;
            const int e = h * HWID + ct * 16 + lr;
            const float yv = acc[ct][r] * inv[r] * bf2f(G[(size_t)q * EMB + e]);
            Y[(size_t)q * EMB + e] = f2bf(yv);
        }
}

// ---------------------------------------------------------------------------
extern "C" void kernel_launch(void* const* d_in, const int* in_sizes, int n_in,
                              void* d_out, int out_size, void* d_ws, size_t ws_size,
                              hipStream_t stream) {
    const float*         x      = (const float*)d_in[0];
    const unsigned char* mask   = (const unsigned char*)d_in[1];
    const float*         bias   = (const float*)d_in[2];
    const float*         w_proj = (const float*)d_in[3];
    const float*         w_o    = (const float*)d_in[4];
    const float*         b_o    = (const float*)d_in[5];
    const float*         w_g    = (const float*)d_in[6];
    const float*         b_g    = (const float*)d_in[7];
    float* out = (float*)d_out;
    (void)in_sizes; (void)n_in; (void)out_size; (void)ws_size;

    char* p = (char*)d_ws;
    auto alloc = [&](size_t bytes) {
        char* r = p; p += (bytes + 255) & ~(size_t)255; return r;
    };
    unsigned short* xb    = (unsigned short*)alloc((size_t)LSEQ * EMB * 2);
    unsigned short* wcat  = (unsigned short*)alloc((size_t)4 * EMB * EMB * 2);
    unsigned short* wob   = (unsigned short*)alloc((size_t)EMB * EMB * 2);
    unsigned short* T     = (unsigned short*)alloc((size_t)LSEQ * 4096 * 2);
    unsigned short* Qh    = (unsigned short*)alloc((size_t)NH * LSEQ * HWID * 2);
    unsigned short* Kh    = (unsigned short*)alloc((size_t)NH * LSEQ * HWID * 2);
    unsigned short* VT    = (unsigned short*)alloc((size_t)NH * HWID * LSEQ * 2);
    unsigned short* G     = (unsigned short*)alloc((size_t)LSEQ * EMB * 2);
    unsigned short* Yb    = (unsigned short*)alloc((size_t)LSEQ * EMB * 2);
    unsigned char*  vmask = (unsigned char*)alloc(LSEQ);

    convert_kernel<<<1024, 256, 0, stream>>>(x, w_proj, w_g, w_o, xb, wcat, wob);
    decode_mask_kernel<<<1, 256, 0, stream>>>(mask, vmask);
    gemm_bt_kernel<<<dim3(4096 / BN, LSEQ / BM), 256, 0, stream>>>(
        xb, wcat, (void*)T, nullptr, LSEQ, 4096, EMB, 0);
    rearrange_kernel<<<LSEQ, 256, 0, stream>>>(T, b_g, Qh, Kh, G);
    vtrans_kernel<<<NH * (LSEQ / 64), 256, 0, stream>>>(T, VT);
    attn_kernel<<<256, 512, 0, stream>>>(Qh, Kh, VT, G, bias, vmask, Yb);
    gemm_bt_kernel<<<dim3(EMB / BN, LSEQ / BM), 256, 0, stream>>>(
        Yb, wob, (void*)out, b_o, LSEQ, EMB, EMB, 1);
}

// Round 6
// 244.412 us; speedup vs baseline: 1.6093x; 1.1054x over previous
//
#include <hip/hip_runtime.h>
#include <stdint.h>

// Problem constants
#define LSEQ 2048
#define EMB  1024
#define NH   16
#define HWID 64
#define SCALEF 0.125f   // 1/sqrt(64), folded into Q during rearrange

typedef __attribute__((ext_vector_type(4))) float  f32x4;
typedef __attribute__((ext_vector_type(8))) short  bf16x8;   // 8 bf16 in 4 VGPRs (MFMA operand)
typedef __attribute__((ext_vector_type(8))) unsigned short u16x8;
typedef __attribute__((ext_vector_type(4))) unsigned short u16x4;

static __device__ __forceinline__ unsigned short f2bf(float f) {
    union { float f; unsigned int u; } v; v.f = f;
    unsigned int r = (v.u + 0x7FFFu + ((v.u >> 16) & 1u)) >> 16;  // RNE
    return (unsigned short)r;
}
static __device__ __forceinline__ float bf2f(unsigned short h) {
    union { unsigned int u; float f; } v; v.u = ((unsigned int)h) << 16;
    return v.f;
}

static __device__ __forceinline__ void gload_lds16(const void* g, void* l) {
    __builtin_amdgcn_global_load_lds((const __attribute__((address_space(1))) void*)g,
                                     (__attribute__((address_space(3))) void*)l,
                                     16, 0, 0);
}

// ---------------------------------------------------------------------------
// K0: fp32 -> bf16 conversion of x, [w_proj;w_g] (concat as 4096x1024), w_o
// ---------------------------------------------------------------------------
__global__ __launch_bounds__(256) void convert_kernel(
    const float* __restrict__ x, const float* __restrict__ wp,
    const float* __restrict__ wg, const float* __restrict__ wo,
    unsigned short* __restrict__ xb, unsigned short* __restrict__ wcat,
    unsigned short* __restrict__ wob)
{
    const int NX  = (LSEQ * EMB) / 4;
    const int NWP = (3 * EMB * EMB) / 4;
    const int NWG = (EMB * EMB) / 4;
    const int NWO = (EMB * EMB) / 4;
    const int total = NX + NWP + NWG + NWO;
    for (int i = blockIdx.x * blockDim.x + threadIdx.x; i < total;
         i += gridDim.x * blockDim.x) {
        const float4* src; unsigned short* dst; int j;
        if (i < NX)                  { src = (const float4*)x;  dst = xb;                  j = i; }
        else if (i < NX + NWP)       { src = (const float4*)wp; dst = wcat;                j = i - NX; }
        else if (i < NX + NWP + NWG) { src = (const float4*)wg; dst = wcat + 3 * EMB * EMB; j = i - NX - NWP; }
        else                         { src = (const float4*)wo; dst = wob;                 j = i - NX - NWP - NWG; }
        float4 v = src[j];
        u16x4 o;
        o.x = f2bf(v.x); o.y = f2bf(v.y); o.z = f2bf(v.z); o.w = f2bf(v.w);
        *(u16x4*)(dst + (size_t)j * 4) = o;
    }
}

// ---------------------------------------------------------------------------
// Mask decode: tolerate bool(1B) / int32 / float32 encodings.
// ---------------------------------------------------------------------------
__global__ void decode_mask_kernel(const unsigned char* __restrict__ mask,
                                   unsigned char* __restrict__ valid)
{
    __shared__ int cnt;
    if (threadIdx.x == 0) cnt = 0;
    __syncthreads();
    int c = 0;
    for (int i = threadIdx.x; i < LSEQ; i += 256) c += (mask[i] != 0);
    atomicAdd(&cnt, c);
    __syncthreads();
    bool isbyte = cnt > LSEQ / 2;
    for (int k = threadIdx.x; k < LSEQ; k += 256) {
        unsigned char v;
        if (isbyte) v = (mask[k] != 0);
        else        v = ((mask[4*k] | mask[4*k+1] | mask[4*k+2] | mask[4*k+3]) != 0);
        valid[k] = v;
    }
}

// ---------------------------------------------------------------------------
// GEMM: C[M,N] = A[M,K] * B[N,K]^T  (m97-style 128x128, BK=64)
// ---------------------------------------------------------------------------
#define BM 128
#define BN 128
#define BK 64

__global__ __launch_bounds__(256) void gemm_bt_kernel(
    const unsigned short* __restrict__ A, const unsigned short* __restrict__ B,
    void* __restrict__ Cout, const float* __restrict__ biasN,
    int M, int N, int K, int epi)
{
    __shared__ unsigned short As[BM][BK];
    __shared__ unsigned short Bs[BN][BK];
    const int tid  = threadIdx.x;
    const int lane = tid & 63;
    const int w    = tid >> 6;
    const int wr   = w >> 1, wc = w & 1;
    const int row0 = blockIdx.y * BM;
    const int col0 = blockIdx.x * BN;
    const int lr = lane & 15;
    const int lg = lane >> 4;

    f32x4 acc[4][4];
    const f32x4 zf = {0.f, 0.f, 0.f, 0.f};
#pragma unroll
    for (int m = 0; m < 4; ++m)
#pragma unroll
        for (int n = 0; n < 4; ++n) acc[m][n] = zf;

    const char* Ab = (const char*)(A + (size_t)row0 * K);
    const char* Bb = (const char*)(B + (size_t)col0 * K);
    const int Kb = K * 2;

    for (int kt = 0; kt < K; kt += BK) {
#pragma unroll
        for (int i = 0; i < 4; ++i) {
            int o = (i * 256 + tid) * 16;
            int r = o >> 7, cb = o & 127;
            gload_lds16(Ab + (size_t)r * Kb + kt * 2 + cb, (char*)As + o);
        }
#pragma unroll
        for (int i = 0; i < 4; ++i) {
            int o = (i * 256 + tid) * 16;
            int r = o >> 7, cb = o & 127;
            gload_lds16(Bb + (size_t)r * Kb + kt * 2 + cb, (char*)Bs + o);
        }
        __syncthreads();
#pragma unroll
        for (int kk = 0; kk < 2; ++kk) {
            bf16x8 af[4], bfr[4];
            const int lk = kk * 32 + lg * 8;
#pragma unroll
            for (int m = 0; m < 4; ++m) af[m]  = *(const bf16x8*)&As[wr * 64 + m * 16 + lr][lk];
#pragma unroll
            for (int n = 0; n < 4; ++n) bfr[n] = *(const bf16x8*)&Bs[wc * 64 + n * 16 + lr][lk];
#pragma unroll
            for (int m = 0; m < 4; ++m)
#pragma unroll
                for (int n = 0; n < 4; ++n)
                    acc[m][n] = __builtin_amdgcn_mfma_f32_16x16x32_bf16(af[m], bfr[n], acc[m][n], 0, 0, 0);
        }
        __syncthreads();
    }

#pragma unroll
    for (int m = 0; m < 4; ++m)
#pragma unroll
        for (int n = 0; n < 4; ++n) {
            const int col = col0 + wc * 64 + n * 16 + lr;
#pragma unroll
            for (int r = 0; r < 4; ++r) {
                const int row = row0 + wr * 64 + m * 16 + lg * 4 + r;
                if (epi == 0)
                    ((unsigned short*)Cout)[(size_t)row * N + col] = f2bf(acc[m][n][r]);
                else
                    ((float*)Cout)[(size_t)row * N + col] = acc[m][n][r] + biasN[col];
            }
        }
}

// ---------------------------------------------------------------------------
// K2a: rearrange proj output T[L,4096]: Q (pre-scaled by 1/8) / K -> [h][l][64];
// gate -> sigmoid
// ---------------------------------------------------------------------------
__global__ __launch_bounds__(256) void rearrange_kernel(
    const unsigned short* __restrict__ T, const float* __restrict__ bg,
    unsigned short* __restrict__ Qh, unsigned short* __restrict__ Kh,
    unsigned short* __restrict__ G)
{
    const int l = blockIdx.x;
    const int t = threadIdx.x;
    const unsigned short* trow = T + (size_t)l * 4096;
    {
        const int tt = t & 127;
        const int h  = tt >> 3;
        const int c0 = (tt & 7) * 8;
        const bool isq = (t < 128);
        const int srcoff = h * 192 + (isq ? 0 : 64) + c0;
        u16x8 v = *(const u16x8*)(trow + srcoff);
        if (isq) {
#pragma unroll
            for (int j = 0; j < 8; ++j) v[j] = f2bf(bf2f(v[j]) * SCALEF);
        }
        unsigned short* dst = (isq ? Qh : Kh) + ((size_t)h * LSEQ + l) * HWID + c0;
        *(u16x8*)dst = v;
    }
    {
        const int f0 = t * 4;
        float4 b4 = *(const float4*)(bg + f0);
        u16x4 tv = *(const u16x4*)(trow + 3 * EMB + f0);
        u16x4 o;
        o.x = f2bf(1.f / (1.f + __expf(-(bf2f(tv.x) + b4.x))));
        o.y = f2bf(1.f / (1.f + __expf(-(bf2f(tv.y) + b4.y))));
        o.z = f2bf(1.f / (1.f + __expf(-(bf2f(tv.z) + b4.z))));
        o.w = f2bf(1.f / (1.f + __expf(-(bf2f(tv.w) + b4.w))));
        *(u16x4*)(G + (size_t)l * EMB + f0) = o;
    }
}

// ---------------------------------------------------------------------------
// K2b: V transpose -> VT[h][c][l] via 64x64 LDS tiles
// ---------------------------------------------------------------------------
__global__ __launch_bounds__(256) void vtrans_kernel(
    const unsigned short* __restrict__ T, unsigned short* __restrict__ VT)
{
    __shared__ unsigned short tile[64][72];
    const int h  = blockIdx.x & 15;
    const int lt = blockIdx.x >> 4;
    const int l0 = lt * 64;
    const int t  = threadIdx.x;
    {
        const int i = t >> 2, c0 = (t & 3) * 16;
        const unsigned short* src = T + (size_t)(l0 + i) * 4096 + h * 192 + 128;
        *(u16x8*)&tile[i][c0]     = *(const u16x8*)(src + c0);
        *(u16x8*)&tile[i][c0 + 8] = *(const u16x8*)(src + c0 + 8);
    }
    __syncthreads();
    {
        const int c = t >> 2, j0 = (t & 3) * 16;
        unsigned short* dst = VT + ((size_t)h * HWID + c) * LSEQ + l0 + j0;
        u16x8 a, b;
#pragma unroll
        for (int j = 0; j < 8; ++j) a[j] = tile[j0 + j][c];
#pragma unroll
        for (int j = 0; j < 8; ++j) b[j] = tile[j0 + 8 + j][c];
        *(u16x8*)dst       = a;
        *(u16x8*)(dst + 8) = b;
    }
}

// ---------------------------------------------------------------------------
// K3: fused attention. Counted-vmcnt ring + co-residency.
// Grid 512 = 64qt x 4hg x 2sp; block 512 thr = 8 waves (4 heads x 2
// q-subtiles); LDS 76KB -> 2 blocks/CU = 16 waves of TLP.
// Ring slot (32KB) = bias [32q][32k]xf32x4h + K (4h x 32k x 128B,
// XOR-swizzled chunks: stored c4 holds source chunk c4^(k&7) -> conflict-free
// ds_read_b128). V is direct global b128 with 1-body register ping-pong
// prefetch. Per body the only vmem: V(t+1) 4 ops + stage(t+2) 4 ops; the
// asm vmcnt(8) at loop top is the single drain point -> stage flies a full
// body; compiler's V-wait = vmcnt(8) (never drains the stage queue).
// ---------------------------------------------------------------------------
#define NT 32          // 1024 keys per split / KT=32
#define SLOT 32768     // bias 16K | K 16K

__global__ __launch_bounds__(512, 4) void attn_kernel(
    const unsigned short* __restrict__ Qh, const unsigned short* __restrict__ Kh,
    const unsigned short* __restrict__ VT, const float* __restrict__ bias,
    const unsigned char* __restrict__ valid,
    float* __restrict__ Op, float* __restrict__ Ml)
{
    __shared__ char ring[2][SLOT];               // 64 KB
    __shared__ unsigned short ps[8][16][40];     // 10 KB per-wave P buffers
    __shared__ unsigned char vld[LSEQ];          // 2 KB

    const int tid  = threadIdx.x;
    const int lane = tid & 63;
    const int w    = tid >> 6;
    // bi = hg*128 + qt*2 + sp : XCD = bi%8 = (qt*2+sp)%8 -> the 4 hg-siblings
    // of each (qt,sp) share one XCD's L2 (bias lines fetched once).
    const int bi = blockIdx.x;
    const int hg = bi >> 7;
    const int u  = bi & 127;
    const int qt = u >> 1;
    const int sp = u & 1;
    const int h4 = hg * 4;
    const int h    = h4 + (w & 3);
    const int q0b  = qt * 32;
    const int q0w  = q0b + (w >> 2) * 16;
    const int koff = sp * 1024;
    const int lr   = lane & 15;
    const int lg   = lane >> 4;
    const int hloc = w & 3;
    const int qloc = (w >> 2) * 16 + lg * 4;

    // Q fragments (registers for the whole kernel)
    const unsigned short* Qbase = Qh + ((size_t)h * LSEQ + q0w) * HWID;
    const bf16x8 qa0 = *(const bf16x8*)(Qbase + lr * HWID + lg * 8);
    const bf16x8 qa1 = *(const bf16x8*)(Qbase + lr * HWID + 32 + lg * 8);

    const unsigned short* Vbase = VT + (size_t)h * HWID * LSEQ;
    const char* bias_base = (const char*)bias;
    const unsigned short* Khb = Kh;

    // mask -> LDS, then one-time full sync (loop never drains)
    {
        uchar4 m4 = *(const uchar4*)(valid + tid * 4);
        *(uchar4*)(vld + tid * 4) = m4;
    }
    __syncthreads();

    // stage tile t into ring[t&1]: 4 x 16B gload_lds per thread
    auto stage = [&](int t) {
        char* base = ring[t & 1];
        const int kg = koff + t * 32;
#pragma unroll
        for (int p2 = 0; p2 < 2; ++p2) {   // bias: 1024 chunks (q=jj>>5, k=jj&31)
            const int jj = p2 * 512 + tid;
            const int q = jj >> 5, k = jj & 31;
            gload_lds16(bias_base + (((size_t)(q0b + q) * LSEQ + kg + k) * NH + h4) * 4,
                        base + jj * 16);
        }
#pragma unroll
        for (int p2 = 0; p2 < 2; ++p2) {   // K: swizzled source chunk c4^(k&7)
            const int jj = p2 * 512 + tid;
            const int hl = jj >> 8, k = (jj >> 3) & 31, c4 = jj & 7;
            gload_lds16(Khb + ((size_t)(h4 + hl) * LSEQ + kg + k) * HWID + ((c4 ^ (k & 7)) * 8),
                        base + 16384 + jj * 16);
        }
    };

    float mrow[4], lrow[4];
    f32x4 acc[4];
    const f32x4 zf = {0.f, 0.f, 0.f, 0.f};
#pragma unroll
    for (int r = 0; r < 4; ++r) { mrow[r] = -1e30f; lrow[r] = 0.f; }
#pragma unroll
    for (int c = 0; c < 4; ++c) acc[c] = zf;

    stage(0);
    stage(1);
    bf16x8 vb_cur[4], vb_nxt[4];
#pragma unroll
    for (int ct = 0; ct < 4; ++ct)
        vb_cur[ct] = *(const bf16x8*)(Vbase + (size_t)(ct * 16 + lr) * LSEQ + koff + lg * 8);

    for (int t = 0; t < NT; ++t) {
        asm volatile("s_waitcnt vmcnt(8)" ::: "memory");
        __builtin_amdgcn_s_barrier();
        asm volatile("" ::: "memory");

        const char* base = ring[t & 1];
        const int kg = koff + t * 32;
        const int kx = lr & 7;

        // K fragments from LDS (swizzled read -> conflict-free)
        const unsigned short* klds = (const unsigned short*)(base + 16384);
        bf16x8 kb[2][2];
#pragma unroll
        for (int t2 = 0; t2 < 2; ++t2) {
            const int krow = (hloc * 32 + t2 * 16 + lr) * HWID;
            kb[t2][0] = *(const bf16x8*)(klds + krow + ((lg ^ kx) * 8));
            kb[t2][1] = *(const bf16x8*)(klds + krow + (((lg + 4) ^ kx) * 8));
        }

        // QK^T
        f32x4 S[2];
#pragma unroll
        for (int t2 = 0; t2 < 2; ++t2) {
            f32x4 s = zf;
            s = __builtin_amdgcn_mfma_f32_16x16x32_bf16(qa0, kb[t2][0], s, 0, 0, 0);
            s = __builtin_amdgcn_mfma_f32_16x16x32_bf16(qa1, kb[t2][1], s, 0, 0, 0);
            S[t2] = s;
        }

        // V(t+1) register prefetch (older than stage(t+2) -> PV wait never
        // drains the stage queue; t=NT-1 reloads tile NT-1, harmless)
        {
            const int kgn = koff + (t + 1 < NT ? t + 1 : t) * 32;
#pragma unroll
            for (int ct = 0; ct < 4; ++ct)
                vb_nxt[ct] = *(const bf16x8*)(Vbase + (size_t)(ct * 16 + lr) * LSEQ + kgn + lg * 8);
        }

        const bool v0 = vld[kg + lr] != 0;
        const bool v1 = vld[kg + 16 + lr] != 0;

        // scores from LDS bias
        const float* bsf = (const float*)base;
        float sc[2][4], rm[4];
#pragma unroll
        for (int r = 0; r < 4; ++r) {
            const float b0 = bsf[((qloc + r) * 32 + lr) * 4 + hloc];
            const float b1 = bsf[((qloc + r) * 32 + 16 + lr) * 4 + hloc];
            sc[0][r] = v0 ? (S[0][r] + b0) : -1e30f;
            sc[1][r] = v1 ? (S[1][r] + b1) : -1e30f;
            rm[r] = fmaxf(sc[0][r], sc[1][r]);
        }
#pragma unroll
        for (int off = 1; off < 16; off <<= 1)
#pragma unroll
            for (int r = 0; r < 4; ++r)
                rm[r] = fmaxf(rm[r], __shfl_xor(rm[r], off, 64));

        // defer-max (T13): only rescale when the tile max grew by > 8
        const float need = fmaxf(fmaxf(rm[0] - mrow[0], rm[1] - mrow[1]),
                                 fmaxf(rm[2] - mrow[2], rm[3] - mrow[3]));
        if (!__all(need <= 8.0f)) {
            float sf[4];
#pragma unroll
            for (int r = 0; r < 4; ++r) {
                const float mn = fmaxf(mrow[r], rm[r]);
                sf[r] = __expf(mrow[r] - mn);
                mrow[r] = mn;
                lrow[r] *= sf[r];
            }
#pragma unroll
            for (int ct = 0; ct < 4; ++ct)
#pragma unroll
                for (int r = 0; r < 4; ++r) acc[ct][r] *= sf[r];
        }

        float rs[4], p0[4], p1[4];
#pragma unroll
        for (int r = 0; r < 4; ++r) {
            p0[r] = v0 ? __expf(sc[0][r] - mrow[r]) : 0.f;
            p1[r] = v1 ? __expf(sc[1][r] - mrow[r]) : 0.f;
            rs[r] = p0[r] + p1[r];
        }
#pragma unroll
        for (int off = 1; off < 16; off <<= 1)
#pragma unroll
            for (int r = 0; r < 4; ++r)
                rs[r] += __shfl_xor(rs[r], off, 64);
#pragma unroll
        for (int r = 0; r < 4; ++r) lrow[r] += rs[r];

        // P -> per-wave LDS (S-layout write, A-frag read)
#pragma unroll
        for (int r = 0; r < 4; ++r) {
            ps[w][lg * 4 + r][lr]      = f2bf(p0[r]);
            ps[w][lg * 4 + r][16 + lr] = f2bf(p1[r]);
        }
        const bf16x8 pa = *(const bf16x8*)&ps[w][lr][lg * 8];

        // PV with current V registers
#pragma unroll
        for (int ct = 0; ct < 4; ++ct)
            acc[ct] = __builtin_amdgcn_mfma_f32_16x16x32_bf16(pa, vb_cur[ct], acc[ct], 0, 0, 0);

        asm volatile("" ::: "memory");
        __builtin_amdgcn_s_barrier();        // all reads of slot t&1 done
        asm volatile("" ::: "memory");
        if (t + 2 <= NT) stage(t + 2 < NT ? t + 2 : NT - 1);

#pragma unroll
        for (int ct = 0; ct < 4; ++ct) vb_cur[ct] = vb_nxt[ct];
    }

    // store partials (unnormalized)
    const size_t rowb = ((size_t)sp * NH + h) * LSEQ;
#pragma unroll
    for (int ct = 0; ct < 4; ++ct)
#pragma unroll
        for (int r = 0; r < 4; ++r) {
            const int q = q0w + lg * 4 + r;
            Op[(rowb + q) * HWID + ct * 16 + lr] = acc[ct][r];
        }
    if (lr == 0) {
#pragma unroll
        for (int r = 0; r < 4; ++r) {
            const int q = q0w + lg * 4 + r;
            Ml[(rowb + q) * 2 + 0] = mrow[r];
            Ml[(rowb + q) * 2 + 1] = lrow[r];
        }
    }
}

// ---------------------------------------------------------------------------
// K3b: combine split-k partials, normalize, apply gate -> bf16 Y
// ---------------------------------------------------------------------------
__global__ __launch_bounds__(256) void combine_kernel(
    const float* __restrict__ Op, const float* __restrict__ Ml,
    const unsigned short* __restrict__ G, unsigned short* __restrict__ Yb)
{
    const int t   = threadIdx.x;
    const int c   = t & 63;
    const int row = blockIdx.x * 4 + (t >> 6);      // [0, NH*LSEQ)
    const int h   = row >> 11;
    const int q   = row & (LSEQ - 1);
    const size_t r0 = (size_t)h * LSEQ + q;
    const size_t r1 = ((size_t)NH + h) * LSEQ + q;
    const float m0 = Ml[r0 * 2 + 0], l0 = Ml[r0 * 2 + 1];
    const float m1 = Ml[r1 * 2 + 0], l1 = Ml[r1 * 2 + 1];
    const float mx = fmaxf(m0, m1);
    const float a0 = __expf(m0 - mx), a1 = __expf(m1 - mx);
    const float inv = 1.f / (l0 * a0 + l1 * a1);
    const float o0 = Op[r0 * HWID + c];
    const float o1 = Op[r1 * HWID + c];
    const float y = (o0 * a0 + o1 * a1) * inv;
    const int e = h * HWID + c;
    const float g = bf2f(G[(size_t)q * EMB + e]);
    Yb[(size_t)q * EMB + e] = f2bf(y * g);
}

// ---------------------------------------------------------------------------
extern "C" void kernel_launch(void* const* d_in, const int* in_sizes, int n_in,
                              void* d_out, int out_size, void* d_ws, size_t ws_size,
                              hipStream_t stream) {
    const float*         x      = (const float*)d_in[0];
    const unsigned char* mask   = (const unsigned char*)d_in[1];
    const float*         bias   = (const float*)d_in[2];
    const float*         w_proj = (const float*)d_in[3];
    const float*         w_o    = (const float*)d_in[4];
    const float*         b_o    = (const float*)d_in[5];
    const float*         w_g    = (const float*)d_in[6];
    const float*         b_g    = (const float*)d_in[7];
    float* out = (float*)d_out;
    (void)in_sizes; (void)n_in; (void)out_size; (void)ws_size;

    char* p = (char*)d_ws;
    auto alloc = [&](size_t bytes) {
        char* r = p; p += (bytes + 255) & ~(size_t)255; return r;
    };
    unsigned short* xb    = (unsigned short*)alloc((size_t)LSEQ * EMB * 2);
    unsigned short* wcat  = (unsigned short*)alloc((size_t)4 * EMB * EMB * 2);
    unsigned short* wob   = (unsigned short*)alloc((size_t)EMB * EMB * 2);
    unsigned short* T     = (unsigned short*)alloc((size_t)LSEQ * 4096 * 2);
    unsigned short* Qh    = (unsigned short*)alloc((size_t)NH * LSEQ * HWID * 2);
    unsigned short* Kh    = (unsigned short*)alloc((size_t)NH * LSEQ * HWID * 2);
    unsigned short* VT    = (unsigned short*)alloc((size_t)NH * HWID * LSEQ * 2);
    unsigned short* G     = (unsigned short*)alloc((size_t)LSEQ * EMB * 2);
    unsigned short* Yb    = (unsigned short*)alloc((size_t)LSEQ * EMB * 2);
    unsigned char*  vmask = (unsigned char*)alloc(LSEQ);
    float*          Op    = (float*)alloc((size_t)2 * NH * LSEQ * HWID * 4);
    float*          Ml    = (float*)alloc((size_t)2 * NH * LSEQ * 2 * 4);

    convert_kernel<<<1024, 256, 0, stream>>>(x, w_proj, w_g, w_o, xb, wcat, wob);
    decode_mask_kernel<<<1, 256, 0, stream>>>(mask, vmask);
    gemm_bt_kernel<<<dim3(4096 / BN, LSEQ / BM), 256, 0, stream>>>(
        xb, wcat, (void*)T, nullptr, LSEQ, 4096, EMB, 0);
    rearrange_kernel<<<LSEQ, 256, 0, stream>>>(T, b_g, Qh, Kh, G);
    vtrans_kernel<<<NH * (LSEQ / 64), 256, 0, stream>>>(T, VT);
    attn_kernel<<<512, 512, 0, stream>>>(Qh, Kh, VT, bias, vmask, Op, Ml);
    combine_kernel<<<NH * LSEQ / 4, 256, 0, stream>>>(Op, Ml, G, Yb);
    gemm_bt_kernel<<<dim3(EMB / BN, LSEQ / BM), 256, 0, stream>>>(
        Yb, wob, (void*)out, b_o, LSEQ, EMB, EMB, 1);
}

// Round 7
// 234.857 us; speedup vs baseline: 1.6748x; 1.0407x over previous
//
#include <hip/hip_runtime.h>
#include <stdint.h>

// Problem constants
#define LSEQ 2048
#define EMB  1024
#define NH   16
#define HWID 64
#define SCALEF 0.125f   // 1/sqrt(64), folded into Q during rearrange

typedef __attribute__((ext_vector_type(4))) float  f32x4;
typedef __attribute__((ext_vector_type(8))) short  bf16x8;   // 8 bf16 in 4 VGPRs (MFMA operand)
typedef __attribute__((ext_vector_type(8))) unsigned short u16x8;
typedef __attribute__((ext_vector_type(4))) unsigned short u16x4;

static __device__ __forceinline__ unsigned short f2bf(float f) {
    union { float f; unsigned int u; } v; v.f = f;
    unsigned int r = (v.u + 0x7FFFu + ((v.u >> 16) & 1u)) >> 16;  // RNE
    return (unsigned short)r;
}
static __device__ __forceinline__ float bf2f(unsigned short h) {
    union { unsigned int u; float f; } v; v.u = ((unsigned int)h) << 16;
    return v.f;
}

static __device__ __forceinline__ void gload_lds16(const void* g, void* l) {
    __builtin_amdgcn_global_load_lds((const __attribute__((address_space(1))) void*)g,
                                     (__attribute__((address_space(3))) void*)l,
                                     16, 0, 0);
}

// ---------------------------------------------------------------------------
// K0: fp32 -> bf16 conversion of x, [w_proj;w_g] (concat as 4096x1024), w_o
// ---------------------------------------------------------------------------
__global__ __launch_bounds__(256) void convert_kernel(
    const float* __restrict__ x, const float* __restrict__ wp,
    const float* __restrict__ wg, const float* __restrict__ wo,
    unsigned short* __restrict__ xb, unsigned short* __restrict__ wcat,
    unsigned short* __restrict__ wob)
{
    const int NX  = (LSEQ * EMB) / 4;
    const int NWP = (3 * EMB * EMB) / 4;
    const int NWG = (EMB * EMB) / 4;
    const int NWO = (EMB * EMB) / 4;
    const int total = NX + NWP + NWG + NWO;
    for (int i = blockIdx.x * blockDim.x + threadIdx.x; i < total;
         i += gridDim.x * blockDim.x) {
        const float4* src; unsigned short* dst; int j;
        if (i < NX)                  { src = (const float4*)x;  dst = xb;                  j = i; }
        else if (i < NX + NWP)       { src = (const float4*)wp; dst = wcat;                j = i - NX; }
        else if (i < NX + NWP + NWG) { src = (const float4*)wg; dst = wcat + 3 * EMB * EMB; j = i - NX - NWP; }
        else                         { src = (const float4*)wo; dst = wob;                 j = i - NX - NWP - NWG; }
        float4 v = src[j];
        u16x4 o;
        o.x = f2bf(v.x); o.y = f2bf(v.y); o.z = f2bf(v.z); o.w = f2bf(v.w);
        *(u16x4*)(dst + (size_t)j * 4) = o;
    }
}

// ---------------------------------------------------------------------------
// Mask decode: tolerate bool(1B) / int32 / float32 encodings.
// ---------------------------------------------------------------------------
__global__ void decode_mask_kernel(const unsigned char* __restrict__ mask,
                                   unsigned char* __restrict__ valid)
{
    __shared__ int cnt;
    if (threadIdx.x == 0) cnt = 0;
    __syncthreads();
    int c = 0;
    for (int i = threadIdx.x; i < LSEQ; i += 256) c += (mask[i] != 0);
    atomicAdd(&cnt, c);
    __syncthreads();
    bool isbyte = cnt > LSEQ / 2;
    for (int k = threadIdx.x; k < LSEQ; k += 256) {
        unsigned char v;
        if (isbyte) v = (mask[k] != 0);
        else        v = ((mask[4*k] | mask[4*k+1] | mask[4*k+2] | mask[4*k+3]) != 0);
        valid[k] = v;
    }
}

// ---------------------------------------------------------------------------
// GEMM: C[M,N] = A[M,K] * B[N,K]^T  (m97-style 128x128, BK=64)
// ---------------------------------------------------------------------------
#define BM 128
#define BN 128
#define BK 64

__global__ __launch_bounds__(256) void gemm_bt_kernel(
    const unsigned short* __restrict__ A, const unsigned short* __restrict__ B,
    void* __restrict__ Cout, const float* __restrict__ biasN,
    int M, int N, int K, int epi)
{
    __shared__ unsigned short As[BM][BK];
    __shared__ unsigned short Bs[BN][BK];
    const int tid  = threadIdx.x;
    const int lane = tid & 63;
    const int w    = tid >> 6;
    const int wr   = w >> 1, wc = w & 1;
    const int row0 = blockIdx.y * BM;
    const int col0 = blockIdx.x * BN;
    const int lr = lane & 15;
    const int lg = lane >> 4;

    f32x4 acc[4][4];
    const f32x4 zf = {0.f, 0.f, 0.f, 0.f};
#pragma unroll
    for (int m = 0; m < 4; ++m)
#pragma unroll
        for (int n = 0; n < 4; ++n) acc[m][n] = zf;

    const char* Ab = (const char*)(A + (size_t)row0 * K);
    const char* Bb = (const char*)(B + (size_t)col0 * K);
    const int Kb = K * 2;

    for (int kt = 0; kt < K; kt += BK) {
#pragma unroll
        for (int i = 0; i < 4; ++i) {
            int o = (i * 256 + tid) * 16;
            int r = o >> 7, cb = o & 127;
            gload_lds16(Ab + (size_t)r * Kb + kt * 2 + cb, (char*)As + o);
        }
#pragma unroll
        for (int i = 0; i < 4; ++i) {
            int o = (i * 256 + tid) * 16;
            int r = o >> 7, cb = o & 127;
            gload_lds16(Bb + (size_t)r * Kb + kt * 2 + cb, (char*)Bs + o);
        }
        __syncthreads();
#pragma unroll
        for (int kk = 0; kk < 2; ++kk) {
            bf16x8 af[4], bfr[4];
            const int lk = kk * 32 + lg * 8;
#pragma unroll
            for (int m = 0; m < 4; ++m) af[m]  = *(const bf16x8*)&As[wr * 64 + m * 16 + lr][lk];
#pragma unroll
            for (int n = 0; n < 4; ++n) bfr[n] = *(const bf16x8*)&Bs[wc * 64 + n * 16 + lr][lk];
#pragma unroll
            for (int m = 0; m < 4; ++m)
#pragma unroll
                for (int n = 0; n < 4; ++n)
                    acc[m][n] = __builtin_amdgcn_mfma_f32_16x16x32_bf16(af[m], bfr[n], acc[m][n], 0, 0, 0);
        }
        __syncthreads();
    }

#pragma unroll
    for (int m = 0; m < 4; ++m)
#pragma unroll
        for (int n = 0; n < 4; ++n) {
            const int col = col0 + wc * 64 + n * 16 + lr;
#pragma unroll
            for (int r = 0; r < 4; ++r) {
                const int row = row0 + wr * 64 + m * 16 + lg * 4 + r;
                if (epi == 0)
                    ((unsigned short*)Cout)[(size_t)row * N + col] = f2bf(acc[m][n][r]);
                else
                    ((float*)Cout)[(size_t)row * N + col] = acc[m][n][r] + biasN[col];
            }
        }
}

// ---------------------------------------------------------------------------
// K2a: rearrange proj output T[L,4096]: Q (pre-scaled by 1/8) / K -> [h][l][64];
// gate -> sigmoid
// ---------------------------------------------------------------------------
__global__ __launch_bounds__(256) void rearrange_kernel(
    const unsigned short* __restrict__ T, const float* __restrict__ bg,
    unsigned short* __restrict__ Qh, unsigned short* __restrict__ Kh,
    unsigned short* __restrict__ G)
{
    const int l = blockIdx.x;
    const int t = threadIdx.x;
    const unsigned short* trow = T + (size_t)l * 4096;
    {
        const int tt = t & 127;
        const int h  = tt >> 3;
        const int c0 = (tt & 7) * 8;
        const bool isq = (t < 128);
        const int srcoff = h * 192 + (isq ? 0 : 64) + c0;
        u16x8 v = *(const u16x8*)(trow + srcoff);
        if (isq) {
#pragma unroll
            for (int j = 0; j < 8; ++j) v[j] = f2bf(bf2f(v[j]) * SCALEF);
        }
        unsigned short* dst = (isq ? Qh : Kh) + ((size_t)h * LSEQ + l) * HWID + c0;
        *(u16x8*)dst = v;
    }
    {
        const int f0 = t * 4;
        float4 b4 = *(const float4*)(bg + f0);
        u16x4 tv = *(const u16x4*)(trow + 3 * EMB + f0);
        u16x4 o;
        o.x = f2bf(1.f / (1.f + __expf(-(bf2f(tv.x) + b4.x))));
        o.y = f2bf(1.f / (1.f + __expf(-(bf2f(tv.y) + b4.y))));
        o.z = f2bf(1.f / (1.f + __expf(-(bf2f(tv.z) + b4.z))));
        o.w = f2bf(1.f / (1.f + __expf(-(bf2f(tv.w) + b4.w))));
        *(u16x4*)(G + (size_t)l * EMB + f0) = o;
    }
}

// ---------------------------------------------------------------------------
// K2b: V transpose -> VT[h][c][l] via 64x64 LDS tiles
// ---------------------------------------------------------------------------
__global__ __launch_bounds__(256) void vtrans_kernel(
    const unsigned short* __restrict__ T, unsigned short* __restrict__ VT)
{
    __shared__ unsigned short tile[64][72];
    const int h  = blockIdx.x & 15;
    const int lt = blockIdx.x >> 4;
    const int l0 = lt * 64;
    const int t  = threadIdx.x;
    {
        const int i = t >> 2, c0 = (t & 3) * 16;
        const unsigned short* src = T + (size_t)(l0 + i) * 4096 + h * 192 + 128;
        *(u16x8*)&tile[i][c0]     = *(const u16x8*)(src + c0);
        *(u16x8*)&tile[i][c0 + 8] = *(const u16x8*)(src + c0 + 8);
    }
    __syncthreads();
    {
        const int c = t >> 2, j0 = (t & 3) * 16;
        unsigned short* dst = VT + ((size_t)h * HWID + c) * LSEQ + l0 + j0;
        u16x8 a, b;
#pragma unroll
        for (int j = 0; j < 8; ++j) a[j] = tile[j0 + j][c];
#pragma unroll
        for (int j = 0; j < 8; ++j) b[j] = tile[j0 + 8 + j][c];
        *(u16x8*)dst       = a;
        *(u16x8*)(dst + 8) = b;
    }
}

// ---------------------------------------------------------------------------
// K3: fused attention, split-k(2), counted-vmcnt pipeline, serial-path-lean
// softmax:
//  - row-sum via ones-MFMA (no shuffle tree)
//  - defer-max (T13): steady state has ZERO cross-lane ops
//  - bias in 4 head-planes stride-33 (<=4-way banks vs 8-way interleaved)
//  - bias staged global->reg->ds_write (T14); K via swizzled global_load_lds;
//    V reg ping-pong. Two vmcnt(4) + two raw barriers per body.
// Queue (steady, per thread): V(t)[4] oldest, stageK(t+1)[2], biasload(t+1)[2].
//  top vmcnt(4): drains V(t), keeps stage.  mid vmcnt(4): drains stage(t+1)
//  (K LDS + bias regs ready), keeps V(t+1) just issued.
// ---------------------------------------------------------------------------
#define NT 32          // tiles per split: 1024 / KT=32

__global__ __launch_bounds__(512, 4) void attn_kernel(
    const unsigned short* __restrict__ Qh, const unsigned short* __restrict__ Kh,
    const unsigned short* __restrict__ VT, const float* __restrict__ bias,
    const unsigned char* __restrict__ valid,
    float* __restrict__ Op, float* __restrict__ Ml)
{
    __shared__ float bias_lds[2][4][1056];       // 33.0 KB: [slot][head][q*33+k]
    __shared__ char kring[2][16384];             // 32 KB: [slot][4h x 32k x 128B]
    __shared__ unsigned short ps[8][16][40];     // 10 KB per-wave P buffers
    __shared__ unsigned char vld[LSEQ];          // 2 KB

    const int tid  = threadIdx.x;
    const int lane = tid & 63;
    const int w    = tid >> 6;
    // bi = hg*128 + qt*2 + sp : XCD = bi%8 shared by the 4 hg-siblings
    const int bi = blockIdx.x;
    const int hg = bi >> 7;
    const int u  = bi & 127;
    const int qt = u >> 1;
    const int sp = u & 1;
    const int h4 = hg * 4;
    const int h    = h4 + (w & 3);
    const int q0b  = qt * 32;
    const int q0w  = q0b + (w >> 2) * 16;
    const int koff = sp * 1024;
    const int lr   = lane & 15;
    const int lg   = lane >> 4;
    const int hloc = w & 3;
    const int qloc = (w >> 2) * 16 + lg * 4;

    // Q fragments (registers for the whole kernel)
    const unsigned short* Qbase = Qh + ((size_t)h * LSEQ + q0w) * HWID;
    const bf16x8 qa0 = *(const bf16x8*)(Qbase + lr * HWID + lg * 8);
    const bf16x8 qa1 = *(const bf16x8*)(Qbase + lr * HWID + 32 + lg * 8);

    const unsigned short* Vbase = VT + (size_t)h * HWID * LSEQ;
    const char* bias_base = (const char*)bias;
    const unsigned short* Khb = Kh;

    bf16x8 ones;
#pragma unroll
    for (int j2 = 0; j2 < 8; ++j2) ones[j2] = (short)0x3F80;  // bf16 1.0

    // K stage via global_load_lds (chunk XOR-swizzle keeps b128 reads even)
    auto stageK = [&](int t) {
        char* base = kring[t & 1];
        const int kg = koff + t * 32;
#pragma unroll
        for (int p2 = 0; p2 < 2; ++p2) {
            const int jj = p2 * 512 + tid;
            const int hl = jj >> 8, k = (jj >> 3) & 31, c4 = jj & 7;
            gload_lds16(Khb + ((size_t)(h4 + hl) * LSEQ + kg + k) * HWID + ((c4 ^ (k & 7)) * 8),
                        base + jj * 16);
        }
    };
    // bias tile -> registers (2 float4/thread)
    auto loadBias = [&](int t, float4* bv) {
        const int kg = koff + t * 32;
#pragma unroll
        for (int p2 = 0; p2 < 2; ++p2) {
            const int jj = p2 * 512 + tid;
            const int q = jj >> 5, k = jj & 31;
            bv[p2] = *(const float4*)(bias_base +
                     (((size_t)(q0b + q) * LSEQ + kg + k) * NH + h4) * 4);
        }
    };
    // registers -> head-plane LDS (stride-33 rows: bank=(q+k)%32)
    auto writeBias = [&](int t, const float4* bv) {
        float (*dst)[1056] = bias_lds[t & 1];
#pragma unroll
        for (int p2 = 0; p2 < 2; ++p2) {
            const int jj = p2 * 512 + tid;
            const int q = jj >> 5, k = jj & 31;
            const int idx = q * 33 + k;
            dst[0][idx] = bv[p2].x;
            dst[1][idx] = bv[p2].y;
            dst[2][idx] = bv[p2].z;
            dst[3][idx] = bv[p2].w;
        }
    };

    float mrow[4];
    f32x4 acc[4], lsum;
    const f32x4 zf = {0.f, 0.f, 0.f, 0.f};
#pragma unroll
    for (int r = 0; r < 4; ++r) mrow[r] = -1e30f;
#pragma unroll
    for (int c = 0; c < 4; ++c) acc[c] = zf;
    lsum = zf;

    // ---- prologue ----
    stageK(0); stageK(1);
    float4 bw0[2], bwW[2], bwN[2];
    loadBias(0, bw0);
    loadBias(1, bwW);
    bf16x8 vb_cur[4], vb_nxt[4];
#pragma unroll
    for (int ct = 0; ct < 4; ++ct)
        vb_cur[ct] = *(const bf16x8*)(Vbase + (size_t)(ct * 16 + lr) * LSEQ + koff + lg * 8);
    {
        uchar4 m4 = *(const uchar4*)(valid + tid * 4);
        *(uchar4*)(vld + tid * 4) = m4;
    }
    __syncthreads();          // one-time full drain (stageK0/1, bias, V0 done)
    writeBias(0, bw0);
    asm volatile("s_waitcnt lgkmcnt(0)" ::: "memory");
    // bias(0) visible after body-0's barrier1

#pragma unroll 1
    for (int t = 0; t < NT; ++t) {
        asm volatile("s_waitcnt vmcnt(4)" ::: "memory");
        __builtin_amdgcn_s_barrier();
        asm volatile("" ::: "memory");

        const char* kbase = kring[t & 1];
        const int kg = koff + t * 32;
        const int kx = lr & 7;

        // K fragments from LDS (swizzled read)
        const unsigned short* klds = (const unsigned short*)kbase;
        bf16x8 kb[2][2];
#pragma unroll
        for (int t2 = 0; t2 < 2; ++t2) {
            const int krow = (hloc * 32 + t2 * 16 + lr) * HWID;
            kb[t2][0] = *(const bf16x8*)(klds + krow + ((lg ^ kx) * 8));
            kb[t2][1] = *(const bf16x8*)(klds + krow + (((lg + 4) ^ kx) * 8));
        }

        // QK^T
        f32x4 S[2];
#pragma unroll
        for (int t2 = 0; t2 < 2; ++t2) {
            f32x4 s = zf;
            s = __builtin_amdgcn_mfma_f32_16x16x32_bf16(qa0, kb[t2][0], s, 0, 0, 0);
            s = __builtin_amdgcn_mfma_f32_16x16x32_bf16(qa1, kb[t2][1], s, 0, 0, 0);
            S[t2] = s;
        }

        // V(t+1) register prefetch
        if (t + 1 < NT) {
            const int kgn = kg + 32;
#pragma unroll
            for (int ct = 0; ct < 4; ++ct)
                vb_nxt[ct] = *(const bf16x8*)(Vbase + (size_t)(ct * 16 + lr) * LSEQ + kgn + lg * 8);
        }

        const bool v0 = vld[kg + lr] != 0;
        const bool v1 = vld[kg + 16 + lr] != 0;

        // scores: S + bias (head-plane LDS, <=4-way banks)
        const float* bpl = bias_lds[t & 1][hloc];
        float sc[2][4];
        float lm[4];
#pragma unroll
        for (int r = 0; r < 4; ++r) {
            const int qrow = (qloc + r) * 33;
            const float b0 = bpl[qrow + lr];
            const float b1 = bpl[qrow + 16 + lr];
            sc[0][r] = v0 ? (S[0][r] + b0) : -1e30f;
            sc[1][r] = v1 ? (S[1][r] + b1) : -1e30f;
            lm[r] = fmaxf(sc[0][r], sc[1][r]);
        }

        // defer-max: steady state = no cross-lane, no rescale
        const float need = fmaxf(fmaxf(lm[0] - mrow[0], lm[1] - mrow[1]),
                                 fmaxf(lm[2] - mrow[2], lm[3] - mrow[3]));
        if (!__all(need <= 8.0f)) {
            float rm[4];
#pragma unroll
            for (int r = 0; r < 4; ++r) rm[r] = lm[r];
#pragma unroll
            for (int off = 1; off < 16; off <<= 1)
#pragma unroll
                for (int r = 0; r < 4; ++r)
                    rm[r] = fmaxf(rm[r], __shfl_xor(rm[r], off, 64));
            float sf[4];
#pragma unroll
            for (int r = 0; r < 4; ++r) {
                const float mn = fmaxf(mrow[r], rm[r]);
                sf[r] = __expf(mrow[r] - mn);
                mrow[r] = mn;
            }
#pragma unroll
            for (int ct = 0; ct < 4; ++ct)
#pragma unroll
                for (int r = 0; r < 4; ++r) acc[ct][r] *= sf[r];
#pragma unroll
            for (int r = 0; r < 4; ++r) lsum[r] *= sf[r];
        }

        // P = exp(sc - mrow); masked lanes give exp(-1e30) = 0
        float p0[4], p1[4];
#pragma unroll
        for (int r = 0; r < 4; ++r) {
            p0[r] = __expf(sc[0][r] - mrow[r]);
            p1[r] = __expf(sc[1][r] - mrow[r]);
        }

        // P -> per-wave LDS (S-layout write, A-frag read)
#pragma unroll
        for (int r = 0; r < 4; ++r) {
            ps[w][lg * 4 + r][lr]      = f2bf(p0[r]);
            ps[w][lg * 4 + r][16 + lr] = f2bf(p1[r]);
        }
        const bf16x8 pa = *(const bf16x8*)&ps[w][lr][lg * 8];

        // PV + row-sum via ones-MFMA
#pragma unroll
        for (int ct = 0; ct < 4; ++ct)
            acc[ct] = __builtin_amdgcn_mfma_f32_16x16x32_bf16(pa, vb_cur[ct], acc[ct], 0, 0, 0);
        lsum = __builtin_amdgcn_mfma_f32_16x16x32_bf16(pa, ones, lsum, 0, 0, 0);

        // bias(t+1): wait its loads (keeps V(t+1) flying), write planes
        if (t + 1 < NT) {
            asm volatile("s_waitcnt vmcnt(4)" ::: "memory");
            writeBias(t + 1, bwW);
        }
        asm volatile("s_waitcnt lgkmcnt(0)" ::: "memory");
        __builtin_amdgcn_s_barrier();
        asm volatile("" ::: "memory");

        // issue next-next prefetches
        if (t + 2 < NT) {
            stageK(t + 2);
            loadBias(t + 2, bwN);
        }
#pragma unroll
        for (int p2 = 0; p2 < 2; ++p2) bwW[p2] = bwN[p2];
#pragma unroll
        for (int ct = 0; ct < 4; ++ct) vb_cur[ct] = vb_nxt[ct];
    }

    // store partials (unnormalized); lsum uniform across the 16 cols of a row
    const size_t rowb = ((size_t)sp * NH + h) * LSEQ;
#pragma unroll
    for (int ct = 0; ct < 4; ++ct)
#pragma unroll
        for (int r = 0; r < 4; ++r) {
            const int q = q0w + lg * 4 + r;
            Op[(rowb + q) * HWID + ct * 16 + lr] = acc[ct][r];
        }
    if (lr == 0) {
#pragma unroll
        for (int r = 0; r < 4; ++r) {
            const int q = q0w + lg * 4 + r;
            Ml[(rowb + q) * 2 + 0] = mrow[r];
            Ml[(rowb + q) * 2 + 1] = lsum[r];
        }
    }
}

// ---------------------------------------------------------------------------
// K3b: combine split-k partials, normalize, apply gate -> bf16 Y
// ---------------------------------------------------------------------------
__global__ __launch_bounds__(256) void combine_kernel(
    const float* __restrict__ Op, const float* __restrict__ Ml,
    const unsigned short* __restrict__ G, unsigned short* __restrict__ Yb)
{
    const int t   = threadIdx.x;
    const int c   = t & 63;
    const int row = blockIdx.x * 4 + (t >> 6);      // [0, NH*LSEQ)
    const int h   = row >> 11;
    const int q   = row & (LSEQ - 1);
    const size_t r0 = (size_t)h * LSEQ + q;
    const size_t r1 = ((size_t)NH + h) * LSEQ + q;
    const float m0 = Ml[r0 * 2 + 0], l0 = Ml[r0 * 2 + 1];
    const float m1 = Ml[r1 * 2 + 0], l1 = Ml[r1 * 2 + 1];
    const float mx = fmaxf(m0, m1);
    const float a0 = __expf(m0 - mx), a1 = __expf(m1 - mx);
    const float inv = 1.f / (l0 * a0 + l1 * a1);
    const float o0 = Op[r0 * HWID + c];
    const float o1 = Op[r1 * HWID + c];
    const float y = (o0 * a0 + o1 * a1) * inv;
    const int e = h * HWID + c;
    const float g = bf2f(G[(size_t)q * EMB + e]);
    Yb[(size_t)q * EMB + e] = f2bf(y * g);
}

// ---------------------------------------------------------------------------
extern "C" void kernel_launch(void* const* d_in, const int* in_sizes, int n_in,
                              void* d_out, int out_size, void* d_ws, size_t ws_size,
                              hipStream_t stream) {
    const float*         x      = (const float*)d_in[0];
    const unsigned char* mask   = (const unsigned char*)d_in[1];
    const float*         bias   = (const float*)d_in[2];
    const float*         w_proj = (const float*)d_in[3];
    const float*         w_o    = (const float*)d_in[4];
    const float*         b_o    = (const float*)d_in[5];
    const float*         w_g    = (const float*)d_in[6];
    const float*         b_g    = (const float*)d_in[7];
    float* out = (float*)d_out;
    (void)in_sizes; (void)n_in; (void)out_size; (void)ws_size;

    char* p = (char*)d_ws;
    auto alloc = [&](size_t bytes) {
        char* r = p; p += (bytes + 255) & ~(size_t)255; return r;
    };
    unsigned short* xb    = (unsigned short*)alloc((size_t)LSEQ * EMB * 2);
    unsigned short* wcat  = (unsigned short*)alloc((size_t)4 * EMB * EMB * 2);
    unsigned short* wob   = (unsigned short*)alloc((size_t)EMB * EMB * 2);
    unsigned short* T     = (unsigned short*)alloc((size_t)LSEQ * 4096 * 2);
    unsigned short* Qh    = (unsigned short*)alloc((size_t)NH * LSEQ * HWID * 2);
    unsigned short* Kh    = (unsigned short*)alloc((size_t)NH * LSEQ * HWID * 2);
    unsigned short* VT    = (unsigned short*)alloc((size_t)NH * HWID * LSEQ * 2);
    unsigned short* G     = (unsigned short*)alloc((size_t)LSEQ * EMB * 2);
    unsigned short* Yb    = (unsigned short*)alloc((size_t)LSEQ * EMB * 2);
    unsigned char*  vmask = (unsigned char*)alloc(LSEQ);
    float*          Op    = (float*)alloc((size_t)2 * NH * LSEQ * HWID * 4);
    float*          Ml    = (float*)alloc((size_t)2 * NH * LSEQ * 2 * 4);

    convert_kernel<<<1024, 256, 0, stream>>>(x, w_proj, w_g, w_o, xb, wcat, wob);
    decode_mask_kernel<<<1, 256, 0, stream>>>(mask, vmask);
    gemm_bt_kernel<<<dim3(4096 / BN, LSEQ / BM), 256, 0, stream>>>(
        xb, wcat, (void*)T, nullptr, LSEQ, 4096, EMB, 0);
    rearrange_kernel<<<LSEQ, 256, 0, stream>>>(T, b_g, Qh, Kh, G);
    vtrans_kernel<<<NH * (LSEQ / 64), 256, 0, stream>>>(T, VT);
    attn_kernel<<<512, 512, 0, stream>>>(Qh, Kh, VT, bias, vmask, Op, Ml);
    combine_kernel<<<NH * LSEQ / 4, 256, 0, stream>>>(Op, Ml, G, Yb);
    gemm_bt_kernel<<<dim3(EMB / BN, LSEQ / BM), 256, 0, stream>>>(
        Yb, wob, (void*)out, b_o, LSEQ, EMB, EMB, 1);
}